// Round 14
// baseline (945.927 us; speedup 1.0000x reference)
//
#include <hip/hip_runtime.h>
#include <cstdint>
#include <cstddef>

#define DI __device__ __forceinline__

constexpr int N = 50000;
constexpr int E = 800000;
constexpr int NG = 8;

// ---------- ws layout ----------
constexpr size_t AL(size_t x){ return (x + 1023) & ~size_t(1023); }
constexpr size_t OFF_SCAL   = 0;                          // 4 doubles (norm sums)
constexpr size_t OFF_GSUM   = 1024;                       // 512 floats
constexpr size_t OFF_GCNT   = OFF_GSUM + 2048;            // 8 floats
constexpr size_t OFF_DEG    = 4096;                       // N ints
constexpr size_t ZERO_BYTES = OFF_DEG + size_t(N)*4;      // zeroed each launch
constexpr size_t OFF_ROWPTR = AL(ZERO_BYTES);             // (N+1) ints
constexpr size_t OFF_CURSOR = AL(OFF_ROWPTR + size_t(N+1)*4);
constexpr size_t OFF_BSUM   = AL(OFF_CURSOR + size_t(N)*4);
constexpr size_t OFF_BOFF   = AL(OFF_BSUM + 1024);
constexpr size_t OFF_COLSRC = AL(OFF_BOFF + 1024);        // E ints
constexpr size_t OFF_COLDST = AL(OFF_COLSRC + size_t(E)*4);   // E ints
constexpr size_t OFF_EAC    = AL(OFF_COLDST + size_t(E)*4);   // E*8 u32 (16 f16)
constexpr size_t OFF_BL     = AL(OFF_EAC + size_t(E)*32);     // N*64 u32 (f16 pairs)
constexpr size_t OFF_BR     = AL(OFF_BL + size_t(N)*64*4);    // N*64 u32 (f16 pairs)
constexpr size_t OFF_A      = AL(OFF_BR + size_t(N)*64*4);    // N*64 u32 (layer input, f16 pairs)
constexpr size_t OFF_CACC   = AL(OFF_A + size_t(N)*64*4);     // N*128 f (atomic acc)
constexpr size_t OFF_DACC   = AL(OFF_CACC + size_t(N)*128*4); // N*2 f
constexpr size_t CACC_ZERO  = (OFF_DACC - OFF_CACC) + size_t(N)*2*4;
// total ~98 MB

template<int START>
DI float wred(float v){
  #pragma unroll
  for (int o = START; o > 0; o >>= 1) v += __shfl_xor(v, o);
  return v;
}

DI float elu(float v){ return v > 0.f ? v : (__expf(v) - 1.f); }

// ---------- f16 pack/unpack helpers ----------
typedef __attribute__((ext_vector_type(2))) __fp16 h2v;

DI uint32_t pkh(float a, float b){
  auto r = __builtin_amdgcn_cvt_pkrtz(a, b);   // v_cvt_pkrtz_f16_f32
  return __builtin_bit_cast(uint32_t, r);
}
DI float hlo(uint32_t u){ h2v h = __builtin_bit_cast(h2v, u); return (float)h.x; }
DI float hhi(uint32_t u){ h2v h = __builtin_bit_cast(h2v, u); return (float)h.y; }
DI float h2f(uint16_t u){ __fp16 h = __builtin_bit_cast(__fp16, u); return (float)h; }

// 2-way f16 dot-accumulate: c += a.x*b.x + a.y*b.y
#if __has_builtin(__builtin_amdgcn_fdot2)
DI float dot2(uint32_t a, uint32_t b, float c){
  return __builtin_amdgcn_fdot2(__builtin_bit_cast(h2v, a),
                                __builtin_bit_cast(h2v, b), c, false);
}
#else
DI float dot2(uint32_t a, uint32_t b, float c){
  return fmaf(hlo(a), hlo(b), fmaf(hhi(a), hhi(b), c));
}
#endif

// ---------- CSR build ----------
__global__ void k_deg(const int* __restrict__ ei, int* __restrict__ deg){
  for (int e = blockIdx.x*blockDim.x + threadIdx.x; e < E; e += gridDim.x*blockDim.x)
    atomicAdd(&deg[ei[E + e]], 1);
}

__global__ __launch_bounds__(256) void k_scan1(const int* __restrict__ deg,
                                               int* __restrict__ rowptr,
                                               int* __restrict__ bsum){
  __shared__ int s[256];
  int t = threadIdx.x, i = blockIdx.x*256 + t;
  int v = (i < N) ? deg[i] : 0;
  s[t] = v; __syncthreads();
  for (int off = 1; off < 256; off <<= 1){
    int x = (t >= off) ? s[t-off] : 0;
    __syncthreads();
    s[t] += x; __syncthreads();
  }
  if (i < N) rowptr[i] = s[t] - v;
  if (t == 255) bsum[blockIdx.x] = s[255];
}

__global__ __launch_bounds__(256) void k_scan2(const int* __restrict__ bsum,
                                               int* __restrict__ boff, int nb){
  __shared__ int s[256];
  int t = threadIdx.x;
  int v = (t < nb) ? bsum[t] : 0;
  s[t] = v; __syncthreads();
  for (int off = 1; off < 256; off <<= 1){
    int x = (t >= off) ? s[t-off] : 0;
    __syncthreads();
    s[t] += x; __syncthreads();
  }
  if (t < nb) boff[t] = s[t] - v;
}

__global__ __launch_bounds__(256) void k_scan3(int* __restrict__ rowptr,
                                               const int* __restrict__ boff,
                                               int* __restrict__ cursor){
  int t = threadIdx.x, i = blockIdx.x*256 + t;
  if (i < N){
    int v = rowptr[i] + boff[blockIdx.x];
    rowptr[i] = v;
    cursor[i] = v;
  }
  if (i == 0) rowptr[N] = E;
}

// fill: CSR src+dst + edge_attr re-ordered into CSR order, f16-packed
__global__ void k_fill(const int* __restrict__ ei, const float* __restrict__ ea,
                       int* __restrict__ cursor, int* __restrict__ colsrc,
                       int* __restrict__ coldst, uint32_t* __restrict__ eac){
  for (int e = blockIdx.x*blockDim.x + threadIdx.x; e < E; e += gridDim.x*blockDim.x){
    int dn = ei[E + e];
    int pos = atomicAdd(&cursor[dn], 1);
    colsrc[pos] = ei[e];
    coldst[pos] = dn;
    const float4* s = (const float4*)(ea + size_t(e)*16);
    float4 v0 = s[0], v1 = s[1], v2 = s[2], v3 = s[3];
    uint32_t* d8 = eac + size_t(pos)*8;
    d8[0] = pkh(v0.x, v0.y); d8[1] = pkh(v0.z, v0.w);
    d8[2] = pkh(v1.x, v1.y); d8[3] = pkh(v1.z, v1.w);
    d8[4] = pkh(v2.x, v2.y); d8[5] = pkh(v2.z, v2.w);
    d8[6] = pkh(v3.x, v3.y); d8[7] = pkh(v3.z, v3.w);
  }
}

// ---------- node transform: A = f16(LN(elu(x @ nt_w + nt_b))) ----------
__global__ __launch_bounds__(256) void k_node_transform(
    const float* __restrict__ x, const float* __restrict__ w,
    const float* __restrict__ b, const float* __restrict__ lnw,
    const float* __restrict__ lnb, uint32_t* __restrict__ A){
  int wid = (blockIdx.x*256 + threadIdx.x) >> 6;
  int l = threadIdx.x & 63;
  if (wid >= N) return;
  float xv = x[wid*32 + (l & 31)];
  float acc = b[l];
  #pragma unroll
  for (int k = 0; k < 32; ++k){
    float hk = __shfl(xv, k);
    acc = fmaf(hk, w[k*64 + l], acc);
  }
  float v = elu(acc);
  float mu = wred<32>(v) * (1.f/64.f);
  float xc = v - mu;
  float var = wred<32>(xc*xc) * (1.f/64.f);
  float rs = rsqrtf(var + 1e-5f);
  float o = xc*rs*lnw[l] + lnb[l];
  float partner = __shfl_xor(o, 1);
  if ((l & 1) == 0) A[wid*32 + (l >> 1)] = pkh(o, partner);
}

// ---------- combined linear (f16-pair input, f16-pair weights in LDS, dot2) ---
template<int K, int C>
__global__ __launch_bounds__(256) void k_lin2(
    const uint32_t* __restrict__ h,   // [N, K/2] f16 pairs
    const float* __restrict__ Wl_, const float* __restrict__ bl_,
    const float* __restrict__ Wr_, const float* __restrict__ br_,
    uint32_t* __restrict__ Bl, uint32_t* __restrict__ Br){
  constexpr int CB = 64;
  constexpr int NL = C / CB;
  constexpr int NCB = 2*NL;
  constexpr int NT = 32;
  constexpr int KQ = K/2;      // u32 words per input row
  constexpr int WQ2 = K/4;     // uint2 per input row
  __shared__ uint32_t Wp[KQ][CB];
  __shared__ uint32_t Hp[NT][KQ + 2];
  const int tid = threadIdx.x;
  const int cb = blockIdx.x % NCB;
  const int tile0 = blockIdx.x / NCB;
  const int tstep = gridDim.x / NCB;
  const bool left = cb < NL;
  const float* W = left ? Wl_ : Wr_;
  const float* bias = left ? bl_ : br_;
  uint32_t* Out = left ? Bl : Br;
  const int wcb = left ? cb : cb - NL;
  for (int idx = tid; idx < KQ*CB; idx += 256){
    int kq = idx >> 6, c = idx & 63;
    Wp[kq][c] = pkh(W[(2*kq)*C + wcb*CB + c], W[(2*kq+1)*C + wcb*CB + c]);
  }
  const int nl = tid >> 4;
  const int cq = tid & 15;
  const float* bb = bias + wcb*CB + cq*4;
  float4 b4 = make_float4(bb[0], bb[1], bb[2], bb[3]);
  constexpr int NTILES = (N + NT - 1)/NT;
  for (int tile = tile0; tile < NTILES; tile += tstep){
    int n0 = tile*NT;
    __syncthreads();
    for (int idx = tid; idx < NT*WQ2; idx += 256){
      int nn = idx / WQ2, q = idx % WQ2;
      uint2 v = make_uint2(0,0);
      int n = n0 + nn;
      if (n < N) v = ((const uint2*)(h + size_t(n)*KQ))[q];
      Hp[nn][2*q]   = v.x;
      Hp[nn][2*q+1] = v.y;
    }
    __syncthreads();
    float4 a0 = make_float4(0,0,0,0), a1 = a0;
    #pragma unroll 8
    for (int kq = 0; kq < KQ; ++kq){
      uint4 w4 = ((const uint4*)&Wp[kq][0])[cq];
      uint32_t h0 = Hp[nl][kq];
      uint32_t h1 = Hp[nl+16][kq];
      a0.x = dot2(h0, w4.x, a0.x); a0.y = dot2(h0, w4.y, a0.y);
      a0.z = dot2(h0, w4.z, a0.z); a0.w = dot2(h0, w4.w, a0.w);
      a1.x = dot2(h1, w4.x, a1.x); a1.y = dot2(h1, w4.y, a1.y);
      a1.z = dot2(h1, w4.z, a1.z); a1.w = dot2(h1, w4.w, a1.w);
    }
    int na = n0 + nl, nb2 = n0 + nl + 16;
    if (na < N){
      uint2 o = make_uint2(pkh(a0.x+b4.x, a0.y+b4.y), pkh(a0.z+b4.z, a0.w+b4.w));
      ((uint2*)(Out + size_t(na)*(C/2)))[wcb*16 + cq] = o;   // row stride C/2 words
    }
    if (nb2 < N){
      uint2 o = make_uint2(pkh(a1.x+b4.x, a1.y+b4.y), pkh(a1.z+b4.z, a1.w+b4.w));
      ((uint2*)(Out + size_t(nb2)*(C/2)))[wcb*16 + cq] = o;
    }
  }
}

// ---------- edge logit helpers (f16 dot2 path) ----------
DI float edge_logit2(float xlx, float xly, float xrx, float xry,
                     const uint32_t* wp0, const uint32_t* wp1, float2 at2,
                     uint4 qa, uint4 qb){
  float c0 = xlx + xrx, c1 = xly + xry;
  uint32_t wq[8] = {qa.x,qa.y,qa.z,qa.w, qb.x,qb.y,qb.z,qb.w};
  #pragma unroll
  for (int k = 0; k < 8; ++k){
    c0 = dot2(wq[k], wp0[k], c0);
    c1 = dot2(wq[k], wp1[k], c1);
  }
  c0 = c0 > 0.f ? c0 : 0.2f*c0;
  c1 = c1 > 0.f ? c1 : 0.2f*c1;
  return wred<16>(c0*at2.x + c1*at2.y);   // per-head reduce within 32-lane half
}

DI float edge_logit1(float xl, float xr, const uint32_t* wp, float at,
                     uint4 qa, uint4 qb){
  float c0 = xl + xr;
  uint32_t wq[8] = {qa.x,qa.y,qa.z,qa.w, qb.x,qb.y,qb.z,qb.w};
  #pragma unroll
  for (int k = 0; k < 8; ++k) c0 = dot2(wq[k], wp[k], c0);
  c0 = c0 > 0.f ? c0 : 0.2f*c0;
  return wred<32>(c0*at);
}

// ---------- fused attention + aggregate: balanced 32-edge chunks + atomics ----
constexpr int CHUNK = 32;
constexpr int NCHUNK = E / CHUNK;   // 25000 exactly

template<int H>
__global__ __launch_bounds__(256, 8) void k_attagg(
    const uint32_t* __restrict__ Bl, const uint32_t* __restrict__ Br,
    const float* __restrict__ we, const float* __restrict__ att,
    const uint32_t* __restrict__ eac,
    const int* __restrict__ colsrc, const int* __restrict__ coldst,
    float* __restrict__ Cacc, float* __restrict__ Dacc){
  const int tid = threadIdx.x;
  const int l = tid & 63;
  const int g = (blockIdx.x*256 + tid) >> 6;
  if (g >= NCHUNK) return;
  const int e0 = g*CHUNK;
  const uint4* eb = (const uint4*)eac;
  const int cs = colsrc[e0 + (l & 31)];
  const int cd = coldst[e0 + (l & 31)];
  if constexpr (H == 2){
    // lane l handles channels (2l, 2l+1) of the 128-wide output
    uint32_t wp0[8], wp1[8];
    #pragma unroll
    for (int k = 0; k < 8; ++k){
      wp0[k] = pkh(we[(2*k)*128 + 2*l],   we[(2*k+1)*128 + 2*l]);
      wp1[k] = pkh(we[(2*k)*128 + 2*l+1], we[(2*k+1)*128 + 2*l+1]);
    }
    const float2 at2 = ((const float2*)att)[l];
    int cur = __shfl(cd, 0);
    uint32_t xrw = Br[size_t(cur)*64 + l];
    float xrx = hlo(xrw), xry = hhi(xrw);
    float d = 0.f, a0 = 0.f, a1 = 0.f;
    #pragma unroll 1
    for (int jb = 0; jb < CHUNK; jb += 4){
      int s0 = __shfl(cs, jb),   s1 = __shfl(cs, jb+1);
      int s2 = __shfl(cs, jb+2), s3 = __shfl(cs, jb+3);
      // issue all 4 gathers + 8 ea loads up front
      uint32_t x0 = Bl[size_t(s0)*64 + l];
      uint32_t x1 = Bl[size_t(s1)*64 + l];
      uint32_t x2 = Bl[size_t(s2)*64 + l];
      uint32_t x3 = Bl[size_t(s3)*64 + l];
      const uint4* q = eb + size_t(e0 + jb)*2;
      uint4 qa0 = q[0], qb0 = q[1], qa1 = q[2], qb1 = q[3];
      uint4 qa2 = q[4], qb2 = q[5], qa3 = q[6], qb3 = q[7];
      int d0 = __shfl(cd, jb),   d1 = __shfl(cd, jb+1);
      int d2 = __shfl(cd, jb+2), d3 = __shfl(cd, jb+3);
      #define FLUSH2(dn) { \
        atomicAdd(&Cacc[size_t(cur)*128 + 2*l],   a0); \
        atomicAdd(&Cacc[size_t(cur)*128 + 2*l+1], a1); \
        if (l == 0)  atomicAdd(&Dacc[cur*2],   d); \
        if (l == 32) atomicAdd(&Dacc[cur*2+1], d); \
        cur = dn; xrw = Br[size_t(cur)*64 + l]; \
        xrx = hlo(xrw); xry = hhi(xrw); d = a0 = a1 = 0.f; }
      #define EDGE2(xk, qak, qbk) { \
        float t = edge_logit2(hlo(xk), hhi(xk), xrx, xry, wp0, wp1, at2, qak, qbk); \
        float p = __expf(t); d += p; \
        a0 = fmaf(p, hlo(xk), a0); a1 = fmaf(p, hhi(xk), a1); }
      if (d0 != cur) FLUSH2(d0); EDGE2(x0, qa0, qb0);
      if (d1 != cur) FLUSH2(d1); EDGE2(x1, qa1, qb1);
      if (d2 != cur) FLUSH2(d2); EDGE2(x2, qa2, qb2);
      if (d3 != cur) FLUSH2(d3); EDGE2(x3, qa3, qb3);
      #undef FLUSH2
      #undef EDGE2
    }
    atomicAdd(&Cacc[size_t(cur)*128 + 2*l],   a0);
    atomicAdd(&Cacc[size_t(cur)*128 + 2*l+1], a1);
    if (l == 0)  atomicAdd(&Dacc[cur*2],   d);
    if (l == 32) atomicAdd(&Dacc[cur*2+1], d);
  } else {
    // lane l handles channel l of the 64-wide output
    uint32_t wp[8];
    #pragma unroll
    for (int k = 0; k < 8; ++k)
      wp[k] = pkh(we[(2*k)*64 + l], we[(2*k+1)*64 + l]);
    const float at = att[l];
    const uint16_t* Bl16 = (const uint16_t*)Bl;
    const uint16_t* Br16 = (const uint16_t*)Br;
    int cur = __shfl(cd, 0);
    float xr = h2f(Br16[size_t(cur)*64 + l]);
    float d = 0.f, a0 = 0.f;
    #pragma unroll 1
    for (int jb = 0; jb < CHUNK; jb += 4){
      int s0 = __shfl(cs, jb),   s1 = __shfl(cs, jb+1);
      int s2 = __shfl(cs, jb+2), s3 = __shfl(cs, jb+3);
      float x0 = h2f(Bl16[size_t(s0)*64 + l]);
      float x1 = h2f(Bl16[size_t(s1)*64 + l]);
      float x2 = h2f(Bl16[size_t(s2)*64 + l]);
      float x3 = h2f(Bl16[size_t(s3)*64 + l]);
      const uint4* q = eb + size_t(e0 + jb)*2;
      uint4 qa0 = q[0], qb0 = q[1], qa1 = q[2], qb1 = q[3];
      uint4 qa2 = q[4], qb2 = q[5], qa3 = q[6], qb3 = q[7];
      int d0 = __shfl(cd, jb),   d1 = __shfl(cd, jb+1);
      int d2 = __shfl(cd, jb+2), d3 = __shfl(cd, jb+3);
      #define FLUSH1(dn) { \
        atomicAdd(&Cacc[size_t(cur)*64 + l], a0); \
        if (l == 0) atomicAdd(&Dacc[cur], d); \
        cur = dn; xr = h2f(Br16[size_t(cur)*64 + l]); d = a0 = 0.f; }
      #define EDGE1(xk, qak, qbk) { \
        float t = edge_logit1(xk, xr, wp, at, qak, qbk); \
        float p = __expf(t); d += p; a0 = fmaf(p, xk, a0); }
      if (d0 != cur) FLUSH1(d0); EDGE1(x0, qa0, qb0);
      if (d1 != cur) FLUSH1(d1); EDGE1(x1, qa1, qb1);
      if (d2 != cur) FLUSH1(d2); EDGE1(x2, qa2, qb2);
      if (d3 != cur) FLUSH1(d3); EDGE1(x3, qa3, qb3);
      #undef FLUSH1
      #undef EDGE1
    }
    atomicAdd(&Cacc[size_t(cur)*64 + l], a0);
    if (l == 0) atomicAdd(&Dacc[cur], d);
  }
}

// ---------- finish (H=2): A = f16(Cacc/d + bias), optional GN stats ----------
template<bool GN>
__global__ __launch_bounds__(256) void k_finish2(
    const float* __restrict__ Cacc, const float* __restrict__ Dacc,
    const float* __restrict__ bias, uint32_t* __restrict__ A,
    double* __restrict__ scal){
  float s1p = 0.f, s2p = 0.f;
  for (int i = blockIdx.x*256 + threadIdx.x; i < N*64; i += gridDim.x*256){
    int n = i >> 6, w = i & 63;
    float inv = 1.f/(Dacc[n*2 + (w >> 5)] + 1e-16f);
    float o0 = Cacc[size_t(n)*128 + 2*w]   * inv + bias[2*w];
    float o1 = Cacc[size_t(n)*128 + 2*w+1] * inv + bias[2*w+1];
    A[i] = pkh(o0, o1);
    if constexpr (GN){ s1p += o0 + o1; s2p += o0*o0 + o1*o1; }
  }
  if constexpr (GN){
    float s = wred<32>(s1p), s2 = wred<32>(s2p);
    __shared__ float bs[4], bs2[4];
    int w = threadIdx.x >> 6;
    if ((threadIdx.x & 63) == 0){ bs[w] = s; bs2[w] = s2; }
    __syncthreads();
    if (threadIdx.x == 0){
      double ts  = (double)bs[0] + (double)bs[1] + (double)bs[2] + (double)bs[3];
      double ts2 = (double)bs2[0] + (double)bs2[1] + (double)bs2[2] + (double)bs2[3];
      atomicAdd(&scal[0], ts);
      atomicAdd(&scal[1], ts2);
    }
  }
}

// ---------- graph norm apply + ELU on f16-pair A (in place) ----------
__global__ __launch_bounds__(256) void k_gn_apply(
    uint32_t* __restrict__ A, const double* __restrict__ scal,
    const float* __restrict__ w, const float* __restrict__ b){
  const double invM = 1.0 / (double(N)*128.0);
  double mu_d = scal[0]*invM;
  double ex2  = scal[1]*invM;
  float mu = (float)mu_d;
  float var = (float)(ex2 - mu_d*mu_d);
  float rs = rsqrtf(var + 1e-5f);
  int i = blockIdx.x*256 + threadIdx.x;
  if (i < N*64){
    int wo = i & 63;
    float2 wv = ((const float2*)w)[wo];
    float2 bv = ((const float2*)b)[wo];
    uint32_t u = A[i];
    float o0 = elu((hlo(u) - mu)*rs*wv.x + bv.x);
    float o1 = elu((hhi(u) - mu)*rs*wv.y + bv.y);
    A[i] = pkh(o0, o1);
  }
}

// ---------- heads + pooling (finish1 fused: v = Cacc/d + bias) ----------
__global__ __launch_bounds__(256) void k_pool(
    const float* __restrict__ Cacc, const float* __restrict__ Dacc,
    const int* __restrict__ batch, const float* __restrict__ bias3,
    const float* __restrict__ pw, const float* __restrict__ pb,
    float* __restrict__ outv, float* __restrict__ gsum, float* __restrict__ gcnt){
  __shared__ float ls[512];
  __shared__ float lc[8];
  int tid = threadIdx.x;
  if (tid < 8) lc[tid] = 0.f;
  for (int i = tid; i < 512; i += 256) ls[i] = 0.f;
  __syncthreads();
  int l = tid & 63;
  int wid = (blockIdx.x*256 + tid) >> 6;
  int NW = (gridDim.x*256) >> 6;
  float pwl = pw[l];
  float b3 = bias3[l];
  for (int n = wid; n < N; n += NW){
    float v = Cacc[size_t(n)*64 + l]/(Dacc[n] + 1e-16f) + b3;
    float pp = wred<32>(v*pwl);
    if (l == 0) outv[n] = pp + pb[0];
    int g = batch[n];
    atomicAdd(&ls[g*64 + l], v);
    if (l == 0) atomicAdd(&lc[g], 1.f);
  }
  __syncthreads();
  for (int i = tid; i < 512; i += 256) atomicAdd(&gsum[i], ls[i]);
  if (tid < 8) atomicAdd(&gcnt[tid], lc[tid]);
}

__global__ __launch_bounds__(512) void k_head(
    const float* __restrict__ gsum, const float* __restrict__ gcnt,
    const float* __restrict__ hw, const float* __restrict__ hb,
    float* __restrict__ outv){
  int g = threadIdx.x >> 6, l = threadIdx.x & 63;
  float cnt = fmaxf(gcnt[g], 1.f);
  float emb = gsum[g*64 + l] / cnt;
  float p = wred<32>(emb*hw[l]);
  if (l == 0) outv[N + g] = p + hb[0];
}

extern "C" void kernel_launch(void* const* d_in, const int* in_sizes, int n_in,
                              void* d_out, int out_size, void* d_ws, size_t ws_size,
                              hipStream_t stream){
  const float* x      = (const float*)d_in[0];
  const int*   ei     = (const int*)  d_in[1];
  const float* ea     = (const float*)d_in[2];
  const int*   batch  = (const int*)  d_in[3];
  const float* nt_w   = (const float*)d_in[4];
  const float* nt_b   = (const float*)d_in[5];
  const float* ln0_w  = (const float*)d_in[6];
  const float* ln0_b  = (const float*)d_in[7];
  const float* c1_wl  = (const float*)d_in[8];
  const float* c1_bl  = (const float*)d_in[9];
  const float* c1_wr  = (const float*)d_in[10];
  const float* c1_br  = (const float*)d_in[11];
  const float* c1_we  = (const float*)d_in[12];
  const float* c1_att = (const float*)d_in[13];
  const float* c1_b   = (const float*)d_in[14];
  const float* n1_w   = (const float*)d_in[15];
  const float* n1_b   = (const float*)d_in[16];
  const float* c2_wl  = (const float*)d_in[17];
  const float* c2_bl  = (const float*)d_in[18];
  const float* c2_wr  = (const float*)d_in[19];
  const float* c2_br  = (const float*)d_in[20];
  const float* c2_we  = (const float*)d_in[21];
  const float* c2_att = (const float*)d_in[22];
  const float* c2_b   = (const float*)d_in[23];
  const float* n2_w   = (const float*)d_in[24];
  const float* n2_b   = (const float*)d_in[25];
  const float* c3_wl  = (const float*)d_in[26];
  const float* c3_bl  = (const float*)d_in[27];
  const float* c3_wr  = (const float*)d_in[28];
  const float* c3_br  = (const float*)d_in[29];
  const float* c3_we  = (const float*)d_in[30];
  const float* c3_att = (const float*)d_in[31];
  const float* c3_b   = (const float*)d_in[32];
  const float* pof_w  = (const float*)d_in[33];
  const float* pof_b  = (const float*)d_in[34];
  const float* hp_w   = (const float*)d_in[35];
  const float* hp_b   = (const float*)d_in[36];
  float* out = (float*)d_out;

  char* w = (char*)d_ws;
  double* scal    = (double*)(w + OFF_SCAL);
  float* gsum     = (float*)(w + OFF_GSUM);
  float* gcnt     = (float*)(w + OFF_GCNT);
  int* deg        = (int*)(w + OFF_DEG);
  int* rowptr     = (int*)(w + OFF_ROWPTR);
  int* cursor     = (int*)(w + OFF_CURSOR);
  int* bsum       = (int*)(w + OFF_BSUM);
  int* boff       = (int*)(w + OFF_BOFF);
  int* colsrc     = (int*)(w + OFF_COLSRC);
  int* coldst     = (int*)(w + OFF_COLDST);
  uint32_t* eac   = (uint32_t*)(w + OFF_EAC);
  uint32_t* Bl    = (uint32_t*)(w + OFF_BL);
  uint32_t* Br    = (uint32_t*)(w + OFF_BR);
  uint32_t* A     = (uint32_t*)(w + OFF_A);
  float* Cacc     = (float*)(w + OFF_CACC);
  float* Dacc     = (float*)(w + OFF_DACC);

  hipMemsetAsync(d_ws, 0, ZERO_BYTES, stream);

  // CSR over dst (shared by all 3 layers) + ea re-order (f16)
  k_deg  <<<1024, 256, 0, stream>>>(ei, deg);
  k_scan1<<<196,  256, 0, stream>>>(deg, rowptr, bsum);
  k_scan2<<<1,    256, 0, stream>>>(bsum, boff, 196);
  k_scan3<<<196,  256, 0, stream>>>(rowptr, boff, cursor);
  k_fill <<<1024, 256, 0, stream>>>(ei, ea, cursor, colsrc, coldst, eac);

  k_node_transform<<<12500, 256, 0, stream>>>(x, nt_w, nt_b, ln0_w, ln0_b, A);

  // layer 1 (in 64, heads 2)
  hipMemsetAsync(w + OFF_CACC, 0, CACC_ZERO, stream);
  k_lin2<64,128><<<2048, 256, 0, stream>>>(A, c1_wl, c1_bl, c1_wr, c1_br, Bl, Br);
  k_attagg<2><<<6250, 256, 0, stream>>>(Bl, Br, c1_we, c1_att, eac, colsrc, coldst, Cacc, Dacc);
  k_finish2<true><<<608, 256, 0, stream>>>(Cacc, Dacc, c1_b, A, scal);
  k_gn_apply<<<12500, 256, 0, stream>>>(A, scal, n1_w, n1_b);

  // layer 2 (in 128, heads 2)
  hipMemsetAsync(w + OFF_CACC, 0, CACC_ZERO, stream);
  k_lin2<128,128><<<2048, 256, 0, stream>>>(A, c2_wl, c2_bl, c2_wr, c2_br, Bl, Br);
  k_attagg<2><<<6250, 256, 0, stream>>>(Bl, Br, c2_we, c2_att, eac, colsrc, coldst, Cacc, Dacc);
  k_finish2<true><<<608, 256, 0, stream>>>(Cacc, Dacc, c2_b, A, scal + 2);
  k_gn_apply<<<12500, 256, 0, stream>>>(A, scal + 2, n2_w, n2_b);

  // layer 3 (in 128, heads 1)
  hipMemsetAsync(w + OFF_CACC, 0, CACC_ZERO, stream);
  k_lin2<128,64><<<1024, 256, 0, stream>>>(A, c3_wl, c3_bl, c3_wr, c3_br, Bl, Br);
  k_attagg<1><<<6250, 256, 0, stream>>>(Bl, Br, c3_we, c3_att, eac, colsrc, coldst, Cacc, Dacc);

  // heads + pooling (finish fused)
  k_pool<<<512, 256, 0, stream>>>(Cacc, Dacc, batch, c3_b, pof_w, pof_b, out, gsum, gcnt);
  k_head<<<1, 512, 0, stream>>>(gsum, gcnt, hp_w, hp_b, out);
}

// Round 15
// 625.781 us; speedup vs baseline: 1.5116x; 1.5116x over previous
//
#include <hip/hip_runtime.h>
#include <cstdint>
#include <cstddef>

#define DI __device__ __forceinline__

constexpr int N = 50000;
constexpr int E = 800000;
constexpr int NG = 8;

// ---------- ws layout ----------
constexpr size_t AL(size_t x){ return (x + 1023) & ~size_t(1023); }
constexpr size_t OFF_SCAL   = 0;                          // 4 doubles (norm sums)
constexpr size_t OFF_GSUM   = 1024;                       // 512 floats
constexpr size_t OFF_GCNT   = OFF_GSUM + 2048;            // 8 floats
constexpr size_t OFF_DEG    = 4096;                       // N ints
constexpr size_t ZERO_BYTES = OFF_DEG + size_t(N)*4;      // zeroed each launch
constexpr size_t OFF_ROWPTR = AL(ZERO_BYTES);             // (N+1) ints
constexpr size_t OFF_CURSOR = AL(OFF_ROWPTR + size_t(N+1)*4);
constexpr size_t OFF_BSUM   = AL(OFF_CURSOR + size_t(N)*4);
constexpr size_t OFF_BOFF   = AL(OFF_BSUM + 1024);
constexpr size_t OFF_COLSRC = AL(OFF_BOFF + 1024);        // E ints
constexpr size_t OFF_COLDST = AL(OFF_COLSRC + size_t(E)*4);   // E ints
constexpr size_t OFF_EAC    = AL(OFF_COLDST + size_t(E)*4);   // E*8 u32 (16 f16)
constexpr size_t OFF_BL     = AL(OFF_EAC + size_t(E)*32);     // N*64 u32 (f16 pairs)
constexpr size_t OFF_BR     = AL(OFF_BL + size_t(N)*64*4);    // N*64 u32 (f16 pairs)
constexpr size_t OFF_A      = AL(OFF_BR + size_t(N)*64*4);    // N*64 u32 (layer input, f16 pairs)
constexpr size_t OFF_CACC   = AL(OFF_A + size_t(N)*64*4);     // N*128 f (atomic acc)
constexpr size_t OFF_DACC   = AL(OFF_CACC + size_t(N)*128*4); // N*2 f
constexpr size_t CACC_ZERO  = (OFF_DACC - OFF_CACC) + size_t(N)*2*4;
// total ~98 MB

template<int START>
DI float wred(float v){
  #pragma unroll
  for (int o = START; o > 0; o >>= 1) v += __shfl_xor(v, o);
  return v;
}

DI float elu(float v){ return v > 0.f ? v : (__expf(v) - 1.f); }

// ---------- f16 pack/unpack helpers ----------
typedef __attribute__((ext_vector_type(2))) __fp16 h2v;

DI uint32_t pkh(float a, float b){
  auto r = __builtin_amdgcn_cvt_pkrtz(a, b);   // v_cvt_pkrtz_f16_f32
  return __builtin_bit_cast(uint32_t, r);
}
DI float hlo(uint32_t u){ h2v h = __builtin_bit_cast(h2v, u); return (float)h.x; }
DI float hhi(uint32_t u){ h2v h = __builtin_bit_cast(h2v, u); return (float)h.y; }
DI float h2f(uint16_t u){ __fp16 h = __builtin_bit_cast(__fp16, u); return (float)h; }

// 2-way f16 dot-accumulate: c += a.x*b.x + a.y*b.y
#if __has_builtin(__builtin_amdgcn_fdot2)
DI float dot2(uint32_t a, uint32_t b, float c){
  return __builtin_amdgcn_fdot2(__builtin_bit_cast(h2v, a),
                                __builtin_bit_cast(h2v, b), c, false);
}
#else
DI float dot2(uint32_t a, uint32_t b, float c){
  return fmaf(hlo(a), hlo(b), fmaf(hhi(a), hhi(b), c));
}
#endif

// ---------- CSR build ----------
__global__ void k_deg(const int* __restrict__ ei, int* __restrict__ deg){
  for (int e = blockIdx.x*blockDim.x + threadIdx.x; e < E; e += gridDim.x*blockDim.x)
    atomicAdd(&deg[ei[E + e]], 1);
}

__global__ __launch_bounds__(256) void k_scan1(const int* __restrict__ deg,
                                               int* __restrict__ rowptr,
                                               int* __restrict__ bsum){
  __shared__ int s[256];
  int t = threadIdx.x, i = blockIdx.x*256 + t;
  int v = (i < N) ? deg[i] : 0;
  s[t] = v; __syncthreads();
  for (int off = 1; off < 256; off <<= 1){
    int x = (t >= off) ? s[t-off] : 0;
    __syncthreads();
    s[t] += x; __syncthreads();
  }
  if (i < N) rowptr[i] = s[t] - v;
  if (t == 255) bsum[blockIdx.x] = s[255];
}

__global__ __launch_bounds__(256) void k_scan2(const int* __restrict__ bsum,
                                               int* __restrict__ boff, int nb){
  __shared__ int s[256];
  int t = threadIdx.x;
  int v = (t < nb) ? bsum[t] : 0;
  s[t] = v; __syncthreads();
  for (int off = 1; off < 256; off <<= 1){
    int x = (t >= off) ? s[t-off] : 0;
    __syncthreads();
    s[t] += x; __syncthreads();
  }
  if (t < nb) boff[t] = s[t] - v;
}

__global__ __launch_bounds__(256) void k_scan3(int* __restrict__ rowptr,
                                               const int* __restrict__ boff,
                                               int* __restrict__ cursor){
  int t = threadIdx.x, i = blockIdx.x*256 + t;
  if (i < N){
    int v = rowptr[i] + boff[blockIdx.x];
    rowptr[i] = v;
    cursor[i] = v;
  }
  if (i == 0) rowptr[N] = E;
}

// fill: CSR src+dst + edge_attr re-ordered into CSR order, f16-packed
__global__ void k_fill(const int* __restrict__ ei, const float* __restrict__ ea,
                       int* __restrict__ cursor, int* __restrict__ colsrc,
                       int* __restrict__ coldst, uint32_t* __restrict__ eac){
  for (int e = blockIdx.x*blockDim.x + threadIdx.x; e < E; e += gridDim.x*blockDim.x){
    int dn = ei[E + e];
    int pos = atomicAdd(&cursor[dn], 1);
    colsrc[pos] = ei[e];
    coldst[pos] = dn;
    const float4* s = (const float4*)(ea + size_t(e)*16);
    float4 v0 = s[0], v1 = s[1], v2 = s[2], v3 = s[3];
    uint32_t* d8 = eac + size_t(pos)*8;
    d8[0] = pkh(v0.x, v0.y); d8[1] = pkh(v0.z, v0.w);
    d8[2] = pkh(v1.x, v1.y); d8[3] = pkh(v1.z, v1.w);
    d8[4] = pkh(v2.x, v2.y); d8[5] = pkh(v2.z, v2.w);
    d8[6] = pkh(v3.x, v3.y); d8[7] = pkh(v3.z, v3.w);
  }
}

// ---------- node transform: A = f16(LN(elu(x @ nt_w + nt_b))) ----------
__global__ __launch_bounds__(256) void k_node_transform(
    const float* __restrict__ x, const float* __restrict__ w,
    const float* __restrict__ b, const float* __restrict__ lnw,
    const float* __restrict__ lnb, uint32_t* __restrict__ A){
  int wid = (blockIdx.x*256 + threadIdx.x) >> 6;
  int l = threadIdx.x & 63;
  if (wid >= N) return;
  float xv = x[wid*32 + (l & 31)];
  float acc = b[l];
  #pragma unroll
  for (int k = 0; k < 32; ++k){
    float hk = __shfl(xv, k);
    acc = fmaf(hk, w[k*64 + l], acc);
  }
  float v = elu(acc);
  float mu = wred<32>(v) * (1.f/64.f);
  float xc = v - mu;
  float var = wred<32>(xc*xc) * (1.f/64.f);
  float rs = rsqrtf(var + 1e-5f);
  float o = xc*rs*lnw[l] + lnb[l];
  float partner = __shfl_xor(o, 1);
  if ((l & 1) == 0) A[wid*32 + (l >> 1)] = pkh(o, partner);
}

// ---------- combined linear (f16-pair input, f16-pair weights in LDS, dot2) ---
template<int K, int C>
__global__ __launch_bounds__(256) void k_lin2(
    const uint32_t* __restrict__ h,   // [N, K/2] f16 pairs
    const float* __restrict__ Wl_, const float* __restrict__ bl_,
    const float* __restrict__ Wr_, const float* __restrict__ br_,
    uint32_t* __restrict__ Bl, uint32_t* __restrict__ Br){
  constexpr int CB = 64;
  constexpr int NL = C / CB;
  constexpr int NCB = 2*NL;
  constexpr int NT = 32;
  constexpr int KQ = K/2;      // u32 words per input row
  constexpr int WQ2 = K/4;     // uint2 per input row
  __shared__ uint32_t Wp[KQ][CB];
  __shared__ uint32_t Hp[NT][KQ + 2];
  const int tid = threadIdx.x;
  const int cb = blockIdx.x % NCB;
  const int tile0 = blockIdx.x / NCB;
  const int tstep = gridDim.x / NCB;
  const bool left = cb < NL;
  const float* W = left ? Wl_ : Wr_;
  const float* bias = left ? bl_ : br_;
  uint32_t* Out = left ? Bl : Br;
  const int wcb = left ? cb : cb - NL;
  for (int idx = tid; idx < KQ*CB; idx += 256){
    int kq = idx >> 6, c = idx & 63;
    Wp[kq][c] = pkh(W[(2*kq)*C + wcb*CB + c], W[(2*kq+1)*C + wcb*CB + c]);
  }
  const int nl = tid >> 4;
  const int cq = tid & 15;
  const float* bb = bias + wcb*CB + cq*4;
  float4 b4 = make_float4(bb[0], bb[1], bb[2], bb[3]);
  constexpr int NTILES = (N + NT - 1)/NT;
  for (int tile = tile0; tile < NTILES; tile += tstep){
    int n0 = tile*NT;
    __syncthreads();
    for (int idx = tid; idx < NT*WQ2; idx += 256){
      int nn = idx / WQ2, q = idx % WQ2;
      uint2 v = make_uint2(0,0);
      int n = n0 + nn;
      if (n < N) v = ((const uint2*)(h + size_t(n)*KQ))[q];
      Hp[nn][2*q]   = v.x;
      Hp[nn][2*q+1] = v.y;
    }
    __syncthreads();
    float4 a0 = make_float4(0,0,0,0), a1 = a0;
    #pragma unroll 8
    for (int kq = 0; kq < KQ; ++kq){
      uint4 w4 = ((const uint4*)&Wp[kq][0])[cq];
      uint32_t h0 = Hp[nl][kq];
      uint32_t h1 = Hp[nl+16][kq];
      a0.x = dot2(h0, w4.x, a0.x); a0.y = dot2(h0, w4.y, a0.y);
      a0.z = dot2(h0, w4.z, a0.z); a0.w = dot2(h0, w4.w, a0.w);
      a1.x = dot2(h1, w4.x, a1.x); a1.y = dot2(h1, w4.y, a1.y);
      a1.z = dot2(h1, w4.z, a1.z); a1.w = dot2(h1, w4.w, a1.w);
    }
    int na = n0 + nl, nb2 = n0 + nl + 16;
    if (na < N){
      uint2 o = make_uint2(pkh(a0.x+b4.x, a0.y+b4.y), pkh(a0.z+b4.z, a0.w+b4.w));
      ((uint2*)(Out + size_t(na)*(C/2)))[wcb*16 + cq] = o;   // row stride C/2 words
    }
    if (nb2 < N){
      uint2 o = make_uint2(pkh(a1.x+b4.x, a1.y+b4.y), pkh(a1.z+b4.z, a1.w+b4.w));
      ((uint2*)(Out + size_t(nb2)*(C/2)))[wcb*16 + cq] = o;
    }
  }
}

// ---------- edge logit helpers (f16 dot2 path) ----------
DI float edge_logit2(float xlx, float xly, float xrx, float xry,
                     const uint32_t* wp0, const uint32_t* wp1, float2 at2,
                     uint4 qa, uint4 qb){
  float c0 = xlx + xrx, c1 = xly + xry;
  uint32_t wq[8] = {qa.x,qa.y,qa.z,qa.w, qb.x,qb.y,qb.z,qb.w};
  #pragma unroll
  for (int k = 0; k < 8; ++k){
    c0 = dot2(wq[k], wp0[k], c0);
    c1 = dot2(wq[k], wp1[k], c1);
  }
  c0 = c0 > 0.f ? c0 : 0.2f*c0;
  c1 = c1 > 0.f ? c1 : 0.2f*c1;
  return wred<16>(c0*at2.x + c1*at2.y);   // per-head reduce within 32-lane half
}

DI float edge_logit1(float xl, float xr, const uint32_t* wp, float at,
                     uint4 qa, uint4 qb){
  float c0 = xl + xr;
  uint32_t wq[8] = {qa.x,qa.y,qa.z,qa.w, qb.x,qb.y,qb.z,qb.w};
  #pragma unroll
  for (int k = 0; k < 8; ++k) c0 = dot2(wq[k], wp[k], c0);
  c0 = c0 > 0.f ? c0 : 0.2f*c0;
  return wred<32>(c0*at);
}

// ---------- fused attention + aggregate: balanced 32-edge chunks + atomics ----
// (256,6): VGPR cap ~85 — enough for the 4 gathers + 8 uint4 ea preloads
// (r14 showed (256,8)/32-VGPR rematerializes loads -> 5x FETCH traffic).
constexpr int CHUNK = 32;
constexpr int NCHUNK = E / CHUNK;   // 25000 exactly

template<int H>
__global__ __launch_bounds__(256, 6) void k_attagg(
    const uint32_t* __restrict__ Bl, const uint32_t* __restrict__ Br,
    const float* __restrict__ we, const float* __restrict__ att,
    const uint32_t* __restrict__ eac,
    const int* __restrict__ colsrc, const int* __restrict__ coldst,
    float* __restrict__ Cacc, float* __restrict__ Dacc){
  const int tid = threadIdx.x;
  const int l = tid & 63;
  const int g = (blockIdx.x*256 + tid) >> 6;
  if (g >= NCHUNK) return;
  const int e0 = g*CHUNK;
  const uint4* eb = (const uint4*)eac;
  const int cs = colsrc[e0 + (l & 31)];
  const int cd = coldst[e0 + (l & 31)];
  if constexpr (H == 2){
    // lane l handles channels (2l, 2l+1) of the 128-wide output
    uint32_t wp0[8], wp1[8];
    #pragma unroll
    for (int k = 0; k < 8; ++k){
      wp0[k] = pkh(we[(2*k)*128 + 2*l],   we[(2*k+1)*128 + 2*l]);
      wp1[k] = pkh(we[(2*k)*128 + 2*l+1], we[(2*k+1)*128 + 2*l+1]);
    }
    const float2 at2 = ((const float2*)att)[l];
    int cur = __shfl(cd, 0);
    uint32_t xrw = Br[size_t(cur)*64 + l];
    float xrx = hlo(xrw), xry = hhi(xrw);
    float d = 0.f, a0 = 0.f, a1 = 0.f;
    #pragma unroll 1
    for (int jb = 0; jb < CHUNK; jb += 4){
      int s0 = __shfl(cs, jb),   s1 = __shfl(cs, jb+1);
      int s2 = __shfl(cs, jb+2), s3 = __shfl(cs, jb+3);
      // issue all 4 gathers + 8 ea loads up front
      uint32_t x0 = Bl[size_t(s0)*64 + l];
      uint32_t x1 = Bl[size_t(s1)*64 + l];
      uint32_t x2 = Bl[size_t(s2)*64 + l];
      uint32_t x3 = Bl[size_t(s3)*64 + l];
      const uint4* q = eb + size_t(e0 + jb)*2;
      uint4 qa0 = q[0], qb0 = q[1], qa1 = q[2], qb1 = q[3];
      uint4 qa2 = q[4], qb2 = q[5], qa3 = q[6], qb3 = q[7];
      int d0 = __shfl(cd, jb),   d1 = __shfl(cd, jb+1);
      int d2 = __shfl(cd, jb+2), d3 = __shfl(cd, jb+3);
      #define FLUSH2(dn) { \
        atomicAdd(&Cacc[size_t(cur)*128 + 2*l],   a0); \
        atomicAdd(&Cacc[size_t(cur)*128 + 2*l+1], a1); \
        if (l == 0)  atomicAdd(&Dacc[cur*2],   d); \
        if (l == 32) atomicAdd(&Dacc[cur*2+1], d); \
        cur = dn; xrw = Br[size_t(cur)*64 + l]; \
        xrx = hlo(xrw); xry = hhi(xrw); d = a0 = a1 = 0.f; }
      #define EDGE2(xk, qak, qbk) { \
        float t = edge_logit2(hlo(xk), hhi(xk), xrx, xry, wp0, wp1, at2, qak, qbk); \
        float p = __expf(t); d += p; \
        a0 = fmaf(p, hlo(xk), a0); a1 = fmaf(p, hhi(xk), a1); }
      if (d0 != cur) FLUSH2(d0); EDGE2(x0, qa0, qb0);
      if (d1 != cur) FLUSH2(d1); EDGE2(x1, qa1, qb1);
      if (d2 != cur) FLUSH2(d2); EDGE2(x2, qa2, qb2);
      if (d3 != cur) FLUSH2(d3); EDGE2(x3, qa3, qb3);
      #undef FLUSH2
      #undef EDGE2
    }
    atomicAdd(&Cacc[size_t(cur)*128 + 2*l],   a0);
    atomicAdd(&Cacc[size_t(cur)*128 + 2*l+1], a1);
    if (l == 0)  atomicAdd(&Dacc[cur*2],   d);
    if (l == 32) atomicAdd(&Dacc[cur*2+1], d);
  } else {
    // lane l handles channel l of the 64-wide output
    uint32_t wp[8];
    #pragma unroll
    for (int k = 0; k < 8; ++k)
      wp[k] = pkh(we[(2*k)*64 + l], we[(2*k+1)*64 + l]);
    const float at = att[l];
    const uint16_t* Bl16 = (const uint16_t*)Bl;
    const uint16_t* Br16 = (const uint16_t*)Br;
    int cur = __shfl(cd, 0);
    float xr = h2f(Br16[size_t(cur)*64 + l]);
    float d = 0.f, a0 = 0.f;
    #pragma unroll 1
    for (int jb = 0; jb < CHUNK; jb += 4){
      int s0 = __shfl(cs, jb),   s1 = __shfl(cs, jb+1);
      int s2 = __shfl(cs, jb+2), s3 = __shfl(cs, jb+3);
      float x0 = h2f(Bl16[size_t(s0)*64 + l]);
      float x1 = h2f(Bl16[size_t(s1)*64 + l]);
      float x2 = h2f(Bl16[size_t(s2)*64 + l]);
      float x3 = h2f(Bl16[size_t(s3)*64 + l]);
      const uint4* q = eb + size_t(e0 + jb)*2;
      uint4 qa0 = q[0], qb0 = q[1], qa1 = q[2], qb1 = q[3];
      uint4 qa2 = q[4], qb2 = q[5], qa3 = q[6], qb3 = q[7];
      int d0 = __shfl(cd, jb),   d1 = __shfl(cd, jb+1);
      int d2 = __shfl(cd, jb+2), d3 = __shfl(cd, jb+3);
      #define FLUSH1(dn) { \
        atomicAdd(&Cacc[size_t(cur)*64 + l], a0); \
        if (l == 0) atomicAdd(&Dacc[cur], d); \
        cur = dn; xr = h2f(Br16[size_t(cur)*64 + l]); d = a0 = 0.f; }
      #define EDGE1(xk, qak, qbk) { \
        float t = edge_logit1(xk, xr, wp, at, qak, qbk); \
        float p = __expf(t); d += p; a0 = fmaf(p, xk, a0); }
      if (d0 != cur) FLUSH1(d0); EDGE1(x0, qa0, qb0);
      if (d1 != cur) FLUSH1(d1); EDGE1(x1, qa1, qb1);
      if (d2 != cur) FLUSH1(d2); EDGE1(x2, qa2, qb2);
      if (d3 != cur) FLUSH1(d3); EDGE1(x3, qa3, qb3);
      #undef FLUSH1
      #undef EDGE1
    }
    atomicAdd(&Cacc[size_t(cur)*64 + l], a0);
    if (l == 0) atomicAdd(&Dacc[cur], d);
  }
}

// ---------- finish (H=2): A = f16(Cacc/d + bias), optional GN stats ----------
template<bool GN>
__global__ __launch_bounds__(256) void k_finish2(
    const float* __restrict__ Cacc, const float* __restrict__ Dacc,
    const float* __restrict__ bias, uint32_t* __restrict__ A,
    double* __restrict__ scal){
  float s1p = 0.f, s2p = 0.f;
  for (int i = blockIdx.x*256 + threadIdx.x; i < N*64; i += gridDim.x*256){
    int n = i >> 6, w = i & 63;
    float inv = 1.f/(Dacc[n*2 + (w >> 5)] + 1e-16f);
    float o0 = Cacc[size_t(n)*128 + 2*w]   * inv + bias[2*w];
    float o1 = Cacc[size_t(n)*128 + 2*w+1] * inv + bias[2*w+1];
    A[i] = pkh(o0, o1);
    if constexpr (GN){ s1p += o0 + o1; s2p += o0*o0 + o1*o1; }
  }
  if constexpr (GN){
    float s = wred<32>(s1p), s2 = wred<32>(s2p);
    __shared__ float bs[4], bs2[4];
    int w = threadIdx.x >> 6;
    if ((threadIdx.x & 63) == 0){ bs[w] = s; bs2[w] = s2; }
    __syncthreads();
    if (threadIdx.x == 0){
      double ts  = (double)bs[0] + (double)bs[1] + (double)bs[2] + (double)bs[3];
      double ts2 = (double)bs2[0] + (double)bs2[1] + (double)bs2[2] + (double)bs2[3];
      atomicAdd(&scal[0], ts);
      atomicAdd(&scal[1], ts2);
    }
  }
}

// ---------- graph norm apply + ELU on f16-pair A (in place) ----------
__global__ __launch_bounds__(256) void k_gn_apply(
    uint32_t* __restrict__ A, const double* __restrict__ scal,
    const float* __restrict__ w, const float* __restrict__ b){
  const double invM = 1.0 / (double(N)*128.0);
  double mu_d = scal[0]*invM;
  double ex2  = scal[1]*invM;
  float mu = (float)mu_d;
  float var = (float)(ex2 - mu_d*mu_d);
  float rs = rsqrtf(var + 1e-5f);
  int i = blockIdx.x*256 + threadIdx.x;
  if (i < N*64){
    int wo = i & 63;
    float2 wv = ((const float2*)w)[wo];
    float2 bv = ((const float2*)b)[wo];
    uint32_t u = A[i];
    float o0 = elu((hlo(u) - mu)*rs*wv.x + bv.x);
    float o1 = elu((hhi(u) - mu)*rs*wv.y + bv.y);
    A[i] = pkh(o0, o1);
  }
}

// ---------- heads + pooling (finish1 fused: v = Cacc/d + bias) ----------
__global__ __launch_bounds__(256) void k_pool(
    const float* __restrict__ Cacc, const float* __restrict__ Dacc,
    const int* __restrict__ batch, const float* __restrict__ bias3,
    const float* __restrict__ pw, const float* __restrict__ pb,
    float* __restrict__ outv, float* __restrict__ gsum, float* __restrict__ gcnt){
  __shared__ float ls[512];
  __shared__ float lc[8];
  int tid = threadIdx.x;
  if (tid < 8) lc[tid] = 0.f;
  for (int i = tid; i < 512; i += 256) ls[i] = 0.f;
  __syncthreads();
  int l = tid & 63;
  int wid = (blockIdx.x*256 + tid) >> 6;
  int NW = (gridDim.x*256) >> 6;
  float pwl = pw[l];
  float b3 = bias3[l];
  for (int n = wid; n < N; n += NW){
    float v = Cacc[size_t(n)*64 + l]/(Dacc[n] + 1e-16f) + b3;
    float pp = wred<32>(v*pwl);
    if (l == 0) outv[n] = pp + pb[0];
    int g = batch[n];
    atomicAdd(&ls[g*64 + l], v);
    if (l == 0) atomicAdd(&lc[g], 1.f);
  }
  __syncthreads();
  for (int i = tid; i < 512; i += 256) atomicAdd(&gsum[i], ls[i]);
  if (tid < 8) atomicAdd(&gcnt[tid], lc[tid]);
}

__global__ __launch_bounds__(512) void k_head(
    const float* __restrict__ gsum, const float* __restrict__ gcnt,
    const float* __restrict__ hw, const float* __restrict__ hb,
    float* __restrict__ outv){
  int g = threadIdx.x >> 6, l = threadIdx.x & 63;
  float cnt = fmaxf(gcnt[g], 1.f);
  float emb = gsum[g*64 + l] / cnt;
  float p = wred<32>(emb*hw[l]);
  if (l == 0) outv[N + g] = p + hb[0];
}

extern "C" void kernel_launch(void* const* d_in, const int* in_sizes, int n_in,
                              void* d_out, int out_size, void* d_ws, size_t ws_size,
                              hipStream_t stream){
  const float* x      = (const float*)d_in[0];
  const int*   ei     = (const int*)  d_in[1];
  const float* ea     = (const float*)d_in[2];
  const int*   batch  = (const int*)  d_in[3];
  const float* nt_w   = (const float*)d_in[4];
  const float* nt_b   = (const float*)d_in[5];
  const float* ln0_w  = (const float*)d_in[6];
  const float* ln0_b  = (const float*)d_in[7];
  const float* c1_wl  = (const float*)d_in[8];
  const float* c1_bl  = (const float*)d_in[9];
  const float* c1_wr  = (const float*)d_in[10];
  const float* c1_br  = (const float*)d_in[11];
  const float* c1_we  = (const float*)d_in[12];
  const float* c1_att = (const float*)d_in[13];
  const float* c1_b   = (const float*)d_in[14];
  const float* n1_w   = (const float*)d_in[15];
  const float* n1_b   = (const float*)d_in[16];
  const float* c2_wl  = (const float*)d_in[17];
  const float* c2_bl  = (const float*)d_in[18];
  const float* c2_wr  = (const float*)d_in[19];
  const float* c2_br  = (const float*)d_in[20];
  const float* c2_we  = (const float*)d_in[21];
  const float* c2_att = (const float*)d_in[22];
  const float* c2_b   = (const float*)d_in[23];
  const float* n2_w   = (const float*)d_in[24];
  const float* n2_b   = (const float*)d_in[25];
  const float* c3_wl  = (const float*)d_in[26];
  const float* c3_bl  = (const float*)d_in[27];
  const float* c3_wr  = (const float*)d_in[28];
  const float* c3_br  = (const float*)d_in[29];
  const float* c3_we  = (const float*)d_in[30];
  const float* c3_att = (const float*)d_in[31];
  const float* c3_b   = (const float*)d_in[32];
  const float* pof_w  = (const float*)d_in[33];
  const float* pof_b  = (const float*)d_in[34];
  const float* hp_w   = (const float*)d_in[35];
  const float* hp_b   = (const float*)d_in[36];
  float* out = (float*)d_out;

  char* w = (char*)d_ws;
  double* scal    = (double*)(w + OFF_SCAL);
  float* gsum     = (float*)(w + OFF_GSUM);
  float* gcnt     = (float*)(w + OFF_GCNT);
  int* deg        = (int*)(w + OFF_DEG);
  int* rowptr     = (int*)(w + OFF_ROWPTR);
  int* cursor     = (int*)(w + OFF_CURSOR);
  int* bsum       = (int*)(w + OFF_BSUM);
  int* boff       = (int*)(w + OFF_BOFF);
  int* colsrc     = (int*)(w + OFF_COLSRC);
  int* coldst     = (int*)(w + OFF_COLDST);
  uint32_t* eac   = (uint32_t*)(w + OFF_EAC);
  uint32_t* Bl    = (uint32_t*)(w + OFF_BL);
  uint32_t* Br    = (uint32_t*)(w + OFF_BR);
  uint32_t* A     = (uint32_t*)(w + OFF_A);
  float* Cacc     = (float*)(w + OFF_CACC);
  float* Dacc     = (float*)(w + OFF_DACC);

  hipMemsetAsync(d_ws, 0, ZERO_BYTES, stream);

  // CSR over dst (shared by all 3 layers) + ea re-order (f16)
  k_deg  <<<1024, 256, 0, stream>>>(ei, deg);
  k_scan1<<<196,  256, 0, stream>>>(deg, rowptr, bsum);
  k_scan2<<<1,    256, 0, stream>>>(bsum, boff, 196);
  k_scan3<<<196,  256, 0, stream>>>(rowptr, boff, cursor);
  k_fill <<<1024, 256, 0, stream>>>(ei, ea, cursor, colsrc, coldst, eac);

  k_node_transform<<<12500, 256, 0, stream>>>(x, nt_w, nt_b, ln0_w, ln0_b, A);

  // layer 1 (in 64, heads 2)
  hipMemsetAsync(w + OFF_CACC, 0, CACC_ZERO, stream);
  k_lin2<64,128><<<2048, 256, 0, stream>>>(A, c1_wl, c1_bl, c1_wr, c1_br, Bl, Br);
  k_attagg<2><<<6250, 256, 0, stream>>>(Bl, Br, c1_we, c1_att, eac, colsrc, coldst, Cacc, Dacc);
  k_finish2<true><<<608, 256, 0, stream>>>(Cacc, Dacc, c1_b, A, scal);
  k_gn_apply<<<12500, 256, 0, stream>>>(A, scal, n1_w, n1_b);

  // layer 2 (in 128, heads 2)
  hipMemsetAsync(w + OFF_CACC, 0, CACC_ZERO, stream);
  k_lin2<128,128><<<2048, 256, 0, stream>>>(A, c2_wl, c2_bl, c2_wr, c2_br, Bl, Br);
  k_attagg<2><<<6250, 256, 0, stream>>>(Bl, Br, c2_we, c2_att, eac, colsrc, coldst, Cacc, Dacc);
  k_finish2<true><<<608, 256, 0, stream>>>(Cacc, Dacc, c2_b, A, scal + 2);
  k_gn_apply<<<12500, 256, 0, stream>>>(A, scal + 2, n2_w, n2_b);

  // layer 3 (in 128, heads 1)
  hipMemsetAsync(w + OFF_CACC, 0, CACC_ZERO, stream);
  k_lin2<128,64><<<1024, 256, 0, stream>>>(A, c3_wl, c3_bl, c3_wr, c3_br, Bl, Br);
  k_attagg<1><<<6250, 256, 0, stream>>>(Bl, Br, c3_we, c3_att, eac, colsrc, coldst, Cacc, Dacc);

  // heads + pooling (finish fused)
  k_pool<<<512, 256, 0, stream>>>(Cacc, Dacc, batch, c3_b, pof_w, pof_b, out, gsum, gcnt);
  k_head<<<1, 512, 0, stream>>>(gsum, gcnt, hp_w, hp_b, out);
}

// Round 16
// 622.961 us; speedup vs baseline: 1.5184x; 1.0045x over previous
//
#include <hip/hip_runtime.h>
#include <cstdint>
#include <cstddef>

#define DI __device__ __forceinline__

constexpr int N = 50000;
constexpr int E = 800000;
constexpr int NG = 8;

// ---------- ws layout ----------
constexpr size_t AL(size_t x){ return (x + 1023) & ~size_t(1023); }
constexpr size_t OFF_SCAL   = 0;                          // 4 doubles (norm sums)
constexpr size_t OFF_GSUM   = 1024;                       // 512 floats
constexpr size_t OFF_GCNT   = OFF_GSUM + 2048;            // 8 floats
constexpr size_t OFF_DEG    = 4096;                       // N ints
constexpr size_t ZERO_BYTES = OFF_DEG + size_t(N)*4;      // zeroed each launch
constexpr size_t OFF_ROWPTR = AL(ZERO_BYTES);             // (N+1) ints
constexpr size_t OFF_CURSOR = AL(OFF_ROWPTR + size_t(N+1)*4);
constexpr size_t OFF_BSUM   = AL(OFF_CURSOR + size_t(N)*4);
constexpr size_t OFF_BOFF   = AL(OFF_BSUM + 1024);
constexpr size_t OFF_COLSRC = AL(OFF_BOFF + 1024);        // E ints
constexpr size_t OFF_COLDST = AL(OFF_COLSRC + size_t(E)*4);   // E ints
constexpr size_t OFF_EAC    = AL(OFF_COLDST + size_t(E)*4);   // E*8 u32 (16 f16)
constexpr size_t OFF_BL     = AL(OFF_EAC + size_t(E)*32);     // N*64 u32 (f16 pairs)
constexpr size_t OFF_BR     = AL(OFF_BL + size_t(N)*64*4);    // N*64 u32 (f16 pairs)
constexpr size_t OFF_A      = AL(OFF_BR + size_t(N)*64*4);    // N*64 u32 (layer input, f16 pairs)
constexpr size_t OFF_CACC   = AL(OFF_A + size_t(N)*64*4);     // N*128 f (atomic acc)
constexpr size_t OFF_DACC   = AL(OFF_CACC + size_t(N)*128*4); // N*2 f
constexpr size_t CACC_ZERO  = (OFF_DACC - OFF_CACC) + size_t(N)*2*4;
// total ~98 MB

template<int START>
DI float wred(float v){
  #pragma unroll
  for (int o = START; o > 0; o >>= 1) v += __shfl_xor(v, o);
  return v;
}

DI float elu(float v){ return v > 0.f ? v : (__expf(v) - 1.f); }

// ---------- f16 pack/unpack helpers ----------
typedef __attribute__((ext_vector_type(2))) __fp16 h2v;

DI uint32_t pkh(float a, float b){
  auto r = __builtin_amdgcn_cvt_pkrtz(a, b);   // v_cvt_pkrtz_f16_f32
  return __builtin_bit_cast(uint32_t, r);
}
DI float hlo(uint32_t u){ h2v h = __builtin_bit_cast(h2v, u); return (float)h.x; }
DI float hhi(uint32_t u){ h2v h = __builtin_bit_cast(h2v, u); return (float)h.y; }
DI float h2f(uint16_t u){ __fp16 h = __builtin_bit_cast(__fp16, u); return (float)h; }

// 2-way f16 dot-accumulate: c += a.x*b.x + a.y*b.y
#if __has_builtin(__builtin_amdgcn_fdot2)
DI float dot2(uint32_t a, uint32_t b, float c){
  return __builtin_amdgcn_fdot2(__builtin_bit_cast(h2v, a),
                                __builtin_bit_cast(h2v, b), c, false);
}
#else
DI float dot2(uint32_t a, uint32_t b, float c){
  return fmaf(hlo(a), hlo(b), fmaf(hhi(a), hhi(b), c));
}
#endif

// ---------- CSR build ----------
__global__ void k_deg(const int* __restrict__ ei, int* __restrict__ deg){
  for (int e = blockIdx.x*blockDim.x + threadIdx.x; e < E; e += gridDim.x*blockDim.x)
    atomicAdd(&deg[ei[E + e]], 1);
}

__global__ __launch_bounds__(256) void k_scan1(const int* __restrict__ deg,
                                               int* __restrict__ rowptr,
                                               int* __restrict__ bsum){
  __shared__ int s[256];
  int t = threadIdx.x, i = blockIdx.x*256 + t;
  int v = (i < N) ? deg[i] : 0;
  s[t] = v; __syncthreads();
  for (int off = 1; off < 256; off <<= 1){
    int x = (t >= off) ? s[t-off] : 0;
    __syncthreads();
    s[t] += x; __syncthreads();
  }
  if (i < N) rowptr[i] = s[t] - v;
  if (t == 255) bsum[blockIdx.x] = s[255];
}

__global__ __launch_bounds__(256) void k_scan2(const int* __restrict__ bsum,
                                               int* __restrict__ boff, int nb){
  __shared__ int s[256];
  int t = threadIdx.x;
  int v = (t < nb) ? bsum[t] : 0;
  s[t] = v; __syncthreads();
  for (int off = 1; off < 256; off <<= 1){
    int x = (t >= off) ? s[t-off] : 0;
    __syncthreads();
    s[t] += x; __syncthreads();
  }
  if (t < nb) boff[t] = s[t] - v;
}

__global__ __launch_bounds__(256) void k_scan3(int* __restrict__ rowptr,
                                               const int* __restrict__ boff,
                                               int* __restrict__ cursor){
  int t = threadIdx.x, i = blockIdx.x*256 + t;
  if (i < N){
    int v = rowptr[i] + boff[blockIdx.x];
    rowptr[i] = v;
    cursor[i] = v;
  }
  if (i == 0) rowptr[N] = E;
}

// fill: CSR src+dst + edge_attr re-ordered into CSR order, f16-packed
__global__ void k_fill(const int* __restrict__ ei, const float* __restrict__ ea,
                       int* __restrict__ cursor, int* __restrict__ colsrc,
                       int* __restrict__ coldst, uint32_t* __restrict__ eac){
  for (int e = blockIdx.x*blockDim.x + threadIdx.x; e < E; e += gridDim.x*blockDim.x){
    int dn = ei[E + e];
    int pos = atomicAdd(&cursor[dn], 1);
    colsrc[pos] = ei[e];
    coldst[pos] = dn;
    const float4* s = (const float4*)(ea + size_t(e)*16);
    float4 v0 = s[0], v1 = s[1], v2 = s[2], v3 = s[3];
    uint32_t* d8 = eac + size_t(pos)*8;
    d8[0] = pkh(v0.x, v0.y); d8[1] = pkh(v0.z, v0.w);
    d8[2] = pkh(v1.x, v1.y); d8[3] = pkh(v1.z, v1.w);
    d8[4] = pkh(v2.x, v2.y); d8[5] = pkh(v2.z, v2.w);
    d8[6] = pkh(v3.x, v3.y); d8[7] = pkh(v3.z, v3.w);
  }
}

// ---------- node transform: A = f16(LN(elu(x @ nt_w + nt_b))) ----------
__global__ __launch_bounds__(256) void k_node_transform(
    const float* __restrict__ x, const float* __restrict__ w,
    const float* __restrict__ b, const float* __restrict__ lnw,
    const float* __restrict__ lnb, uint32_t* __restrict__ A){
  int wid = (blockIdx.x*256 + threadIdx.x) >> 6;
  int l = threadIdx.x & 63;
  if (wid >= N) return;
  float xv = x[wid*32 + (l & 31)];
  float acc = b[l];
  #pragma unroll
  for (int k = 0; k < 32; ++k){
    float hk = __shfl(xv, k);
    acc = fmaf(hk, w[k*64 + l], acc);
  }
  float v = elu(acc);
  float mu = wred<32>(v) * (1.f/64.f);
  float xc = v - mu;
  float var = wred<32>(xc*xc) * (1.f/64.f);
  float rs = rsqrtf(var + 1e-5f);
  float o = xc*rs*lnw[l] + lnb[l];
  float partner = __shfl_xor(o, 1);
  if ((l & 1) == 0) A[wid*32 + (l >> 1)] = pkh(o, partner);
}

// ---------- combined linear (f16 dot2). GN=true: apply graph-norm + ELU to the
// input at LDS-staging time (mu/rs from scal; per-channel gw/gb), fusing the
// former k_gn_apply pass.
template<int K, int C, bool GN>
__global__ __launch_bounds__(256) void k_lin2(
    const uint32_t* __restrict__ h,   // [N, K/2] f16 pairs (raw if GN)
    const double* __restrict__ scal,
    const float* __restrict__ gw, const float* __restrict__ gb,
    const float* __restrict__ Wl_, const float* __restrict__ bl_,
    const float* __restrict__ Wr_, const float* __restrict__ br_,
    uint32_t* __restrict__ Bl, uint32_t* __restrict__ Br){
  constexpr int CB = 64;
  constexpr int NL = C / CB;
  constexpr int NCB = 2*NL;
  constexpr int NT = 32;
  constexpr int KQ = K/2;      // u32 words per input row
  constexpr int WQ2 = K/4;     // uint2 per input row
  __shared__ uint32_t Wp[KQ][CB];
  __shared__ uint32_t Hp[NT][KQ + 2];
  const int tid = threadIdx.x;
  const int cb = blockIdx.x % NCB;
  const int tile0 = blockIdx.x / NCB;
  const int tstep = gridDim.x / NCB;
  const bool left = cb < NL;
  const float* W = left ? Wl_ : Wr_;
  const float* bias = left ? bl_ : br_;
  uint32_t* Out = left ? Bl : Br;
  const int wcb = left ? cb : cb - NL;
  float mu = 0.f, rs = 1.f;
  if constexpr (GN){
    const double invM = 1.0 / (double(N)*double(K));
    double mu_d = scal[0]*invM;
    double ex2  = scal[1]*invM;
    mu = (float)mu_d;
    rs = rsqrtf((float)(ex2 - mu_d*mu_d) + 1e-5f);
  }
  for (int idx = tid; idx < KQ*CB; idx += 256){
    int kq = idx >> 6, c = idx & 63;
    Wp[kq][c] = pkh(W[(2*kq)*C + wcb*CB + c], W[(2*kq+1)*C + wcb*CB + c]);
  }
  const int nl = tid >> 4;
  const int cq = tid & 15;
  const float* bb = bias + wcb*CB + cq*4;
  float4 b4 = make_float4(bb[0], bb[1], bb[2], bb[3]);
  constexpr int NTILES = (N + NT - 1)/NT;
  for (int tile = tile0; tile < NTILES; tile += tstep){
    int n0 = tile*NT;
    __syncthreads();
    for (int idx = tid; idx < NT*WQ2; idx += 256){
      int nn = idx / WQ2, q = idx % WQ2;
      uint2 v = make_uint2(0,0);
      int n = n0 + nn;
      if (n < N) v = ((const uint2*)(h + size_t(n)*KQ))[q];
      if constexpr (GN){
        int ch = 4*q;
        float4 wv = *(const float4*)(gw + ch);
        float4 bv = *(const float4*)(gb + ch);
        float o0 = elu((hlo(v.x) - mu)*rs*wv.x + bv.x);
        float o1 = elu((hhi(v.x) - mu)*rs*wv.y + bv.y);
        float o2 = elu((hlo(v.y) - mu)*rs*wv.z + bv.z);
        float o3 = elu((hhi(v.y) - mu)*rs*wv.w + bv.w);
        v.x = pkh(o0, o1);
        v.y = pkh(o2, o3);
      }
      Hp[nn][2*q]   = v.x;
      Hp[nn][2*q+1] = v.y;
    }
    __syncthreads();
    float4 a0 = make_float4(0,0,0,0), a1 = a0;
    #pragma unroll 8
    for (int kq = 0; kq < KQ; ++kq){
      uint4 w4 = ((const uint4*)&Wp[kq][0])[cq];
      uint32_t h0 = Hp[nl][kq];
      uint32_t h1 = Hp[nl+16][kq];
      a0.x = dot2(h0, w4.x, a0.x); a0.y = dot2(h0, w4.y, a0.y);
      a0.z = dot2(h0, w4.z, a0.z); a0.w = dot2(h0, w4.w, a0.w);
      a1.x = dot2(h1, w4.x, a1.x); a1.y = dot2(h1, w4.y, a1.y);
      a1.z = dot2(h1, w4.z, a1.z); a1.w = dot2(h1, w4.w, a1.w);
    }
    int na = n0 + nl, nb2 = n0 + nl + 16;
    if (na < N){
      uint2 o = make_uint2(pkh(a0.x+b4.x, a0.y+b4.y), pkh(a0.z+b4.z, a0.w+b4.w));
      ((uint2*)(Out + size_t(na)*(C/2)))[wcb*16 + cq] = o;   // row stride C/2 words
    }
    if (nb2 < N){
      uint2 o = make_uint2(pkh(a1.x+b4.x, a1.y+b4.y), pkh(a1.z+b4.z, a1.w+b4.w));
      ((uint2*)(Out + size_t(nb2)*(C/2)))[wcb*16 + cq] = o;
    }
  }
}

// ---------- edge logit helpers (f16 dot2 path) ----------
DI float edge_logit2(float xlx, float xly, float xrx, float xry,
                     const uint32_t* wp0, const uint32_t* wp1, float2 at2,
                     uint4 qa, uint4 qb){
  float c0 = xlx + xrx, c1 = xly + xry;
  uint32_t wq[8] = {qa.x,qa.y,qa.z,qa.w, qb.x,qb.y,qb.z,qb.w};
  #pragma unroll
  for (int k = 0; k < 8; ++k){
    c0 = dot2(wq[k], wp0[k], c0);
    c1 = dot2(wq[k], wp1[k], c1);
  }
  c0 = c0 > 0.f ? c0 : 0.2f*c0;
  c1 = c1 > 0.f ? c1 : 0.2f*c1;
  return wred<16>(c0*at2.x + c1*at2.y);   // per-head reduce within 32-lane half
}

DI float edge_logit1(float xl, float xr, const uint32_t* wp, float at,
                     uint4 qa, uint4 qb){
  float c0 = xl + xr;
  uint32_t wq[8] = {qa.x,qa.y,qa.z,qa.w, qb.x,qb.y,qb.z,qb.w};
  #pragma unroll
  for (int k = 0; k < 8; ++k) c0 = dot2(wq[k], wp[k], c0);
  c0 = c0 > 0.f ? c0 : 0.2f*c0;
  return wred<32>(c0*at);
}

// ---------- fused attention + aggregate: balanced 32-edge chunks + atomics ----
// (256,6): VGPR cap ~85 — enough for the 4 gathers + 8 uint4 ea preloads
// (r14 showed (256,8)/32-VGPR rematerializes loads -> 5x FETCH traffic).
constexpr int CHUNK = 32;
constexpr int NCHUNK = E / CHUNK;   // 25000 exactly

template<int H>
__global__ __launch_bounds__(256, 6) void k_attagg(
    const uint32_t* __restrict__ Bl, const uint32_t* __restrict__ Br,
    const float* __restrict__ we, const float* __restrict__ att,
    const uint32_t* __restrict__ eac,
    const int* __restrict__ colsrc, const int* __restrict__ coldst,
    float* __restrict__ Cacc, float* __restrict__ Dacc){
  const int tid = threadIdx.x;
  const int l = tid & 63;
  const int g = (blockIdx.x*256 + tid) >> 6;
  if (g >= NCHUNK) return;
  const int e0 = g*CHUNK;
  const uint4* eb = (const uint4*)eac;
  const int cs = colsrc[e0 + (l & 31)];
  const int cd = coldst[e0 + (l & 31)];
  if constexpr (H == 2){
    // lane l handles channels (2l, 2l+1) of the 128-wide output
    uint32_t wp0[8], wp1[8];
    #pragma unroll
    for (int k = 0; k < 8; ++k){
      wp0[k] = pkh(we[(2*k)*128 + 2*l],   we[(2*k+1)*128 + 2*l]);
      wp1[k] = pkh(we[(2*k)*128 + 2*l+1], we[(2*k+1)*128 + 2*l+1]);
    }
    const float2 at2 = ((const float2*)att)[l];
    int cur = __shfl(cd, 0);
    uint32_t xrw = Br[size_t(cur)*64 + l];
    float xrx = hlo(xrw), xry = hhi(xrw);
    float d = 0.f, a0 = 0.f, a1 = 0.f;
    #pragma unroll 1
    for (int jb = 0; jb < CHUNK; jb += 4){
      int s0 = __shfl(cs, jb),   s1 = __shfl(cs, jb+1);
      int s2 = __shfl(cs, jb+2), s3 = __shfl(cs, jb+3);
      // issue all 4 gathers + 8 ea loads up front
      uint32_t x0 = Bl[size_t(s0)*64 + l];
      uint32_t x1 = Bl[size_t(s1)*64 + l];
      uint32_t x2 = Bl[size_t(s2)*64 + l];
      uint32_t x3 = Bl[size_t(s3)*64 + l];
      const uint4* q = eb + size_t(e0 + jb)*2;
      uint4 qa0 = q[0], qb0 = q[1], qa1 = q[2], qb1 = q[3];
      uint4 qa2 = q[4], qb2 = q[5], qa3 = q[6], qb3 = q[7];
      int d0 = __shfl(cd, jb),   d1 = __shfl(cd, jb+1);
      int d2 = __shfl(cd, jb+2), d3 = __shfl(cd, jb+3);
      #define FLUSH2(dn) { \
        atomicAdd(&Cacc[size_t(cur)*128 + 2*l],   a0); \
        atomicAdd(&Cacc[size_t(cur)*128 + 2*l+1], a1); \
        if (l == 0)  atomicAdd(&Dacc[cur*2],   d); \
        if (l == 32) atomicAdd(&Dacc[cur*2+1], d); \
        cur = dn; xrw = Br[size_t(cur)*64 + l]; \
        xrx = hlo(xrw); xry = hhi(xrw); d = a0 = a1 = 0.f; }
      #define EDGE2(xk, qak, qbk) { \
        float t = edge_logit2(hlo(xk), hhi(xk), xrx, xry, wp0, wp1, at2, qak, qbk); \
        float p = __expf(t); d += p; \
        a0 = fmaf(p, hlo(xk), a0); a1 = fmaf(p, hhi(xk), a1); }
      if (d0 != cur) FLUSH2(d0); EDGE2(x0, qa0, qb0);
      if (d1 != cur) FLUSH2(d1); EDGE2(x1, qa1, qb1);
      if (d2 != cur) FLUSH2(d2); EDGE2(x2, qa2, qb2);
      if (d3 != cur) FLUSH2(d3); EDGE2(x3, qa3, qb3);
      #undef FLUSH2
      #undef EDGE2
    }
    atomicAdd(&Cacc[size_t(cur)*128 + 2*l],   a0);
    atomicAdd(&Cacc[size_t(cur)*128 + 2*l+1], a1);
    if (l == 0)  atomicAdd(&Dacc[cur*2],   d);
    if (l == 32) atomicAdd(&Dacc[cur*2+1], d);
  } else {
    // lane l handles channel l of the 64-wide output
    uint32_t wp[8];
    #pragma unroll
    for (int k = 0; k < 8; ++k)
      wp[k] = pkh(we[(2*k)*64 + l], we[(2*k+1)*64 + l]);
    const float at = att[l];
    const uint16_t* Bl16 = (const uint16_t*)Bl;
    const uint16_t* Br16 = (const uint16_t*)Br;
    int cur = __shfl(cd, 0);
    float xr = h2f(Br16[size_t(cur)*64 + l]);
    float d = 0.f, a0 = 0.f;
    #pragma unroll 1
    for (int jb = 0; jb < CHUNK; jb += 4){
      int s0 = __shfl(cs, jb),   s1 = __shfl(cs, jb+1);
      int s2 = __shfl(cs, jb+2), s3 = __shfl(cs, jb+3);
      float x0 = h2f(Bl16[size_t(s0)*64 + l]);
      float x1 = h2f(Bl16[size_t(s1)*64 + l]);
      float x2 = h2f(Bl16[size_t(s2)*64 + l]);
      float x3 = h2f(Bl16[size_t(s3)*64 + l]);
      const uint4* q = eb + size_t(e0 + jb)*2;
      uint4 qa0 = q[0], qb0 = q[1], qa1 = q[2], qb1 = q[3];
      uint4 qa2 = q[4], qb2 = q[5], qa3 = q[6], qb3 = q[7];
      int d0 = __shfl(cd, jb),   d1 = __shfl(cd, jb+1);
      int d2 = __shfl(cd, jb+2), d3 = __shfl(cd, jb+3);
      #define FLUSH1(dn) { \
        atomicAdd(&Cacc[size_t(cur)*64 + l], a0); \
        if (l == 0) atomicAdd(&Dacc[cur], d); \
        cur = dn; xr = h2f(Br16[size_t(cur)*64 + l]); d = a0 = 0.f; }
      #define EDGE1(xk, qak, qbk) { \
        float t = edge_logit1(xk, xr, wp, at, qak, qbk); \
        float p = __expf(t); d += p; a0 = fmaf(p, xk, a0); }
      if (d0 != cur) FLUSH1(d0); EDGE1(x0, qa0, qb0);
      if (d1 != cur) FLUSH1(d1); EDGE1(x1, qa1, qb1);
      if (d2 != cur) FLUSH1(d2); EDGE1(x2, qa2, qb2);
      if (d3 != cur) FLUSH1(d3); EDGE1(x3, qa3, qb3);
      #undef FLUSH1
      #undef EDGE1
    }
    atomicAdd(&Cacc[size_t(cur)*64 + l], a0);
    if (l == 0) atomicAdd(&Dacc[cur], d);
  }
}

// ---------- finish (H=2): A = f16(Cacc/d + bias), GN stats ----------
template<bool GN>
__global__ __launch_bounds__(256) void k_finish2(
    const float* __restrict__ Cacc, const float* __restrict__ Dacc,
    const float* __restrict__ bias, uint32_t* __restrict__ A,
    double* __restrict__ scal){
  float s1p = 0.f, s2p = 0.f;
  for (int i = blockIdx.x*256 + threadIdx.x; i < N*64; i += gridDim.x*256){
    int n = i >> 6, w = i & 63;
    float inv = 1.f/(Dacc[n*2 + (w >> 5)] + 1e-16f);
    float o0 = Cacc[size_t(n)*128 + 2*w]   * inv + bias[2*w];
    float o1 = Cacc[size_t(n)*128 + 2*w+1] * inv + bias[2*w+1];
    A[i] = pkh(o0, o1);
    if constexpr (GN){ s1p += o0 + o1; s2p += o0*o0 + o1*o1; }
  }
  if constexpr (GN){
    float s = wred<32>(s1p), s2 = wred<32>(s2p);
    __shared__ float bs[4], bs2[4];
    int w = threadIdx.x >> 6;
    if ((threadIdx.x & 63) == 0){ bs[w] = s; bs2[w] = s2; }
    __syncthreads();
    if (threadIdx.x == 0){
      double ts  = (double)bs[0] + (double)bs[1] + (double)bs[2] + (double)bs[3];
      double ts2 = (double)bs2[0] + (double)bs2[1] + (double)bs2[2] + (double)bs2[3];
      atomicAdd(&scal[0], ts);
      atomicAdd(&scal[1], ts2);
    }
  }
}

// ---------- heads + pooling (finish1 fused: v = Cacc/d + bias) ----------
__global__ __launch_bounds__(256) void k_pool(
    const float* __restrict__ Cacc, const float* __restrict__ Dacc,
    const int* __restrict__ batch, const float* __restrict__ bias3,
    const float* __restrict__ pw, const float* __restrict__ pb,
    float* __restrict__ outv, float* __restrict__ gsum, float* __restrict__ gcnt){
  __shared__ float ls[512];
  __shared__ float lc[8];
  int tid = threadIdx.x;
  if (tid < 8) lc[tid] = 0.f;
  for (int i = tid; i < 512; i += 256) ls[i] = 0.f;
  __syncthreads();
  int l = tid & 63;
  int wid = (blockIdx.x*256 + tid) >> 6;
  int NW = (gridDim.x*256) >> 6;
  float pwl = pw[l];
  float b3 = bias3[l];
  for (int n = wid; n < N; n += NW){
    float v = Cacc[size_t(n)*64 + l]/(Dacc[n] + 1e-16f) + b3;
    float pp = wred<32>(v*pwl);
    if (l == 0) outv[n] = pp + pb[0];
    int g = batch[n];
    atomicAdd(&ls[g*64 + l], v);
    if (l == 0) atomicAdd(&lc[g], 1.f);
  }
  __syncthreads();
  for (int i = tid; i < 512; i += 256) atomicAdd(&gsum[i], ls[i]);
  if (tid < 8) atomicAdd(&gcnt[tid], lc[tid]);
}

__global__ __launch_bounds__(512) void k_head(
    const float* __restrict__ gsum, const float* __restrict__ gcnt,
    const float* __restrict__ hw, const float* __restrict__ hb,
    float* __restrict__ outv){
  int g = threadIdx.x >> 6, l = threadIdx.x & 63;
  float cnt = fmaxf(gcnt[g], 1.f);
  float emb = gsum[g*64 + l] / cnt;
  float p = wred<32>(emb*hw[l]);
  if (l == 0) outv[N + g] = p + hb[0];
}

extern "C" void kernel_launch(void* const* d_in, const int* in_sizes, int n_in,
                              void* d_out, int out_size, void* d_ws, size_t ws_size,
                              hipStream_t stream){
  const float* x      = (const float*)d_in[0];
  const int*   ei     = (const int*)  d_in[1];
  const float* ea     = (const float*)d_in[2];
  const int*   batch  = (const int*)  d_in[3];
  const float* nt_w   = (const float*)d_in[4];
  const float* nt_b   = (const float*)d_in[5];
  const float* ln0_w  = (const float*)d_in[6];
  const float* ln0_b  = (const float*)d_in[7];
  const float* c1_wl  = (const float*)d_in[8];
  const float* c1_bl  = (const float*)d_in[9];
  const float* c1_wr  = (const float*)d_in[10];
  const float* c1_br  = (const float*)d_in[11];
  const float* c1_we  = (const float*)d_in[12];
  const float* c1_att = (const float*)d_in[13];
  const float* c1_b   = (const float*)d_in[14];
  const float* n1_w   = (const float*)d_in[15];
  const float* n1_b   = (const float*)d_in[16];
  const float* c2_wl  = (const float*)d_in[17];
  const float* c2_bl  = (const float*)d_in[18];
  const float* c2_wr  = (const float*)d_in[19];
  const float* c2_br  = (const float*)d_in[20];
  const float* c2_we  = (const float*)d_in[21];
  const float* c2_att = (const float*)d_in[22];
  const float* c2_b   = (const float*)d_in[23];
  const float* n2_w   = (const float*)d_in[24];
  const float* n2_b   = (const float*)d_in[25];
  const float* c3_wl  = (const float*)d_in[26];
  const float* c3_bl  = (const float*)d_in[27];
  const float* c3_wr  = (const float*)d_in[28];
  const float* c3_br  = (const float*)d_in[29];
  const float* c3_we  = (const float*)d_in[30];
  const float* c3_att = (const float*)d_in[31];
  const float* c3_b   = (const float*)d_in[32];
  const float* pof_w  = (const float*)d_in[33];
  const float* pof_b  = (const float*)d_in[34];
  const float* hp_w   = (const float*)d_in[35];
  const float* hp_b   = (const float*)d_in[36];
  float* out = (float*)d_out;

  char* w = (char*)d_ws;
  double* scal    = (double*)(w + OFF_SCAL);
  float* gsum     = (float*)(w + OFF_GSUM);
  float* gcnt     = (float*)(w + OFF_GCNT);
  int* deg        = (int*)(w + OFF_DEG);
  int* rowptr     = (int*)(w + OFF_ROWPTR);
  int* cursor     = (int*)(w + OFF_CURSOR);
  int* bsum       = (int*)(w + OFF_BSUM);
  int* boff       = (int*)(w + OFF_BOFF);
  int* colsrc     = (int*)(w + OFF_COLSRC);
  int* coldst     = (int*)(w + OFF_COLDST);
  uint32_t* eac   = (uint32_t*)(w + OFF_EAC);
  uint32_t* Bl    = (uint32_t*)(w + OFF_BL);
  uint32_t* Br    = (uint32_t*)(w + OFF_BR);
  uint32_t* A     = (uint32_t*)(w + OFF_A);
  float* Cacc     = (float*)(w + OFF_CACC);
  float* Dacc     = (float*)(w + OFF_DACC);

  hipMemsetAsync(d_ws, 0, ZERO_BYTES, stream);

  // CSR over dst (shared by all 3 layers) + ea re-order (f16)
  k_deg  <<<1024, 256, 0, stream>>>(ei, deg);
  k_scan1<<<196,  256, 0, stream>>>(deg, rowptr, bsum);
  k_scan2<<<1,    256, 0, stream>>>(bsum, boff, 196);
  k_scan3<<<196,  256, 0, stream>>>(rowptr, boff, cursor);
  k_fill <<<1024, 256, 0, stream>>>(ei, ea, cursor, colsrc, coldst, eac);

  k_node_transform<<<12500, 256, 0, stream>>>(x, nt_w, nt_b, ln0_w, ln0_b, A);

  // layer 1 (in 64, heads 2) — input already LN'd by node_transform
  hipMemsetAsync(w + OFF_CACC, 0, CACC_ZERO, stream);
  k_lin2<64,128,false><<<2048, 256, 0, stream>>>(A, nullptr, nullptr, nullptr,
      c1_wl, c1_bl, c1_wr, c1_br, Bl, Br);
  k_attagg<2><<<6250, 256, 0, stream>>>(Bl, Br, c1_we, c1_att, eac, colsrc, coldst, Cacc, Dacc);
  k_finish2<true><<<608, 256, 0, stream>>>(Cacc, Dacc, c1_b, A, scal);

  // layer 2 (in 128, heads 2) — GN+ELU applied at lin2 staging
  hipMemsetAsync(w + OFF_CACC, 0, CACC_ZERO, stream);
  k_lin2<128,128,true><<<2048, 256, 0, stream>>>(A, scal, n1_w, n1_b,
      c2_wl, c2_bl, c2_wr, c2_br, Bl, Br);
  k_attagg<2><<<6250, 256, 0, stream>>>(Bl, Br, c2_we, c2_att, eac, colsrc, coldst, Cacc, Dacc);
  k_finish2<true><<<608, 256, 0, stream>>>(Cacc, Dacc, c2_b, A, scal + 2);

  // layer 3 (in 128, heads 1) — GN+ELU applied at lin2 staging
  hipMemsetAsync(w + OFF_CACC, 0, CACC_ZERO, stream);
  k_lin2<128,64,true><<<1024, 256, 0, stream>>>(A, scal + 2, n2_w, n2_b,
      c3_wl, c3_bl, c3_wr, c3_br, Bl, Br);
  k_attagg<1><<<6250, 256, 0, stream>>>(Bl, Br, c3_we, c3_att, eac, colsrc, coldst, Cacc, Dacc);

  // heads + pooling (finish fused)
  k_pool<<<512, 256, 0, stream>>>(Cacc, Dacc, batch, c3_b, pof_w, pof_b, out, gsum, gcnt);
  k_head<<<1, 512, 0, stream>>>(gsum, gcnt, hp_w, hp_b, out);
}